// Round 11
// baseline (670.744 us; speedup 1.0000x reference)
//
#include <hip/hip_runtime.h>

// ---------------------------------------------------------------------------
// GCN forward, fp16 datapath + XCD-partitioned CSR build. (round-10 structure;
// aggregate = half-wave paired-row gather, 512B per load-instruction pair)
//   prep:  deg/dinv, CSR(dst)->src (XCD-local scatter), W -> fp16 hi/lo.
//   layer: H' = dinv[r] * (A @ W)        (f16 MFMA, 2 products, split acc)
//          A_next[d] = relu( dinv[d]*(sum_{s in N(d)} H'[s] + H'[d]) + b )
//   pool:  mean over sorted batch ids (fp16 in), then 128->10 head.
// Output: y[512*10] ++ global_mean[512*128], fp32.
// ---------------------------------------------------------------------------

#define ATOMIC_ADD_F32(p, v) __hip_atomic_fetch_add((p), (v), __ATOMIC_RELAXED, __HIP_MEMORY_SCOPE_AGENT)

constexpr int NG = 512;   // NUM_GRAPHS
constexpr float LO_SCALE = 4096.f;      // 2^12
constexpr float LO_INV   = 1.f / 4096.f;

typedef _Float16 half8 __attribute__((ext_vector_type(8)));
typedef float f32x4 __attribute__((ext_vector_type(4)));

// --- degree (XCD-partitioned histogram; deg = in-edge count) -----------------
__global__ __launch_bounds__(256) void k_deg_count_xcd(const int* __restrict__ dst,
                                                       int* __restrict__ deg,
                                                       int E, int N) {
    const int range = blockIdx.x & 7;
    const int chunk = blockIdx.x >> 3;
    const int nchunks = gridDim.x >> 3;
    const int csz = (E + nchunks - 1) / nchunks;
    const int lo = chunk * csz;
    const int hi = min(lo + csz, E);
    const int nr = N / 8;
    const int rlo = range * nr;
    const int rhi = (range == 7) ? N : rlo + nr;
    for (int i = lo + threadIdx.x; i < hi; i += 256) {
        int d = dst[i];
        if (d >= rlo && d < rhi) atomicAdd(&deg[d], 1);
    }
}

// --- exclusive scan of deg -> rowptr; dinv = rsqrt(deg+1) --------------------
__global__ __launch_bounds__(256) void k_scan_local(const int* __restrict__ deg,
                                                    int* __restrict__ rowptr,
                                                    int* __restrict__ partials,
                                                    float* __restrict__ dinv, int N) {
    __shared__ int s[256];
    int t = threadIdx.x;
    int i = blockIdx.x * 256 + t;
    int dg = (i < N) ? deg[i] : 0;
    if (i < N) dinv[i] = rsqrtf((float)(dg + 1));
    s[t] = dg;
    __syncthreads();
#pragma unroll
    for (int off = 1; off < 256; off <<= 1) {
        int add = (t >= off) ? s[t - off] : 0;
        __syncthreads();
        s[t] += add;
        __syncthreads();
    }
    if (i < N) rowptr[i] = s[t] - dg;
    if (t == 255) partials[blockIdx.x] = s[t];
}

__global__ __launch_bounds__(512) void k_scan_partials(int* __restrict__ partials, int nblk) {
    __shared__ int s[512];
    int t = threadIdx.x;
    int v = (t < nblk) ? partials[t] : 0;
    s[t] = v;
    __syncthreads();
#pragma unroll
    for (int off = 1; off < 512; off <<= 1) {
        int add = (t >= off) ? s[t - off] : 0;
        __syncthreads();
        s[t] += add;
        __syncthreads();
    }
    if (t < nblk) partials[t] = s[t] - v;
}

// also seeds cursor = rowptr
__global__ __launch_bounds__(256) void k_scan_apply(const int* __restrict__ deg,
                                                    int* __restrict__ rowptr,
                                                    int* __restrict__ cursor,
                                                    const int* __restrict__ partials, int N) {
    int i = blockIdx.x * 256 + threadIdx.x;
    if (i < N) {
        int r = rowptr[i] + partials[blockIdx.x];
        rowptr[i] = r;
        cursor[i] = r;
        if (i == N - 1) rowptr[N] = r + deg[i];
    }
}

// --- CSR fill, XCD-partitioned ------------------------------------------------
__global__ __launch_bounds__(256) void k_csr_fill_xcd(const int* __restrict__ src,
                                                      const int* __restrict__ dst,
                                                      int* __restrict__ cursor,
                                                      int* __restrict__ csr_src,
                                                      int E, int N) {
    const int range = blockIdx.x & 7;
    const int chunk = blockIdx.x >> 3;
    const int nchunks = gridDim.x >> 3;
    const int csz = (E + nchunks - 1) / nchunks;
    const int lo = chunk * csz;
    const int hi = min(lo + csz, E);
    const int nr = N / 8;
    const int rlo = range * nr;
    const int rhi = (range == 7) ? N : rlo + nr;
    for (int i = lo + threadIdx.x; i < hi; i += 256) {
        int d = dst[i];
        if (d >= rlo && d < rhi) {
            int pos = atomicAdd(&cursor[d], 1);
            csr_src[pos] = src[i];
        }
    }
}

// --- W prep: all 4 layers in one launch ----------------------------------------
struct WSplitArgs {
    const float* W[4];
    _Float16* Wth[4];
    _Float16* Wtl[4];
};
__global__ __launch_bounds__(256) void k_wsplit4(WSplitArgs a) {
    int idx = blockIdx.x * 256 + threadIdx.x;   // 4 * 16384 total
    int layer = idx >> 14;
    int e = idx & 16383;
    int k = e >> 7, c = e & 127;
    float w = a.W[layer][e];
    _Float16 hi = (_Float16)w;
    float lo = (w - (float)hi) * LO_SCALE;
    a.Wth[layer][c * 128 + k] = hi;
    a.Wtl[layer][c * 128 + k] = (_Float16)lo;
}

// --- GEMM: H' = dinv[r] * (A @ W), f16 MFMA, 2 products, split accumulator ---
// AFP32=1: A is fp32 (layer 0, reads X directly); else fp16.
template <int AFP32>
__global__ __launch_bounds__(256) void k_gemm_f16(const void* __restrict__ Aptr,
                                                  const _Float16* __restrict__ Wth,
                                                  const _Float16* __restrict__ Wtl,
                                                  const float* __restrict__ dinv,
                                                  _Float16* __restrict__ Hh, int N) {
    const int tid = threadIdx.x;
    const int wave = tid >> 6;
    const int l = tid & 63;
    const int wrow = wave & 1;
    const int wcol = wave >> 1;
    const int lr = l & 15;
    const int q = l >> 4;

    const int row_base = blockIdx.x * 64 + wrow * 32;
    const int c_base = wcol * 64;

    f32x4 acch[2][4], accl[2][4];
#pragma unroll
    for (int rt = 0; rt < 2; ++rt)
#pragma unroll
        for (int ct = 0; ct < 4; ++ct) {
            acch[rt][ct] = (f32x4){0.f, 0.f, 0.f, 0.f};
            accl[rt][ct] = (f32x4){0.f, 0.f, 0.f, 0.f};
        }

#pragma unroll
    for (int ks = 0; ks < 4; ++ks) {
        const int koff = ks * 32 + q * 8;

        half8 bh[4], bl[4];
#pragma unroll
        for (int ct = 0; ct < 4; ++ct) {
            size_t off = (size_t)(c_base + ct * 16 + lr) * 128 + koff;
            bh[ct] = *(const half8*)(Wth + off);
            bl[ct] = *(const half8*)(Wtl + off);
        }

        half8 a[2];
#pragma unroll
        for (int rt = 0; rt < 2; ++rt) {
            int r = row_base + rt * 16 + lr;
            if (r >= N) r = N - 1;                 // clamp; stores guarded
            if constexpr (AFP32) {
                const float* xp = (const float*)Aptr + (size_t)r * 128 + koff;
                float4 f0 = *(const float4*)xp;
                float4 f1 = *(const float4*)(xp + 4);
                half8 h;
                h[0] = (_Float16)f0.x; h[1] = (_Float16)f0.y;
                h[2] = (_Float16)f0.z; h[3] = (_Float16)f0.w;
                h[4] = (_Float16)f1.x; h[5] = (_Float16)f1.y;
                h[6] = (_Float16)f1.z; h[7] = (_Float16)f1.w;
                a[rt] = h;
            } else {
                a[rt] = *(const half8*)((const _Float16*)Aptr + (size_t)r * 128 + koff);
            }
        }

#pragma unroll
        for (int rt = 0; rt < 2; ++rt)
#pragma unroll
            for (int ct = 0; ct < 4; ++ct) {
                acch[rt][ct] = __builtin_amdgcn_mfma_f32_16x16x32_f16(a[rt], bh[ct], acch[rt][ct], 0, 0, 0);
                accl[rt][ct] = __builtin_amdgcn_mfma_f32_16x16x32_f16(a[rt], bl[ct], accl[rt][ct], 0, 0, 0);
            }
    }

    // store: D frag: col = lane&15, row = q*4 + j ; scale by dinv[row]
#pragma unroll
    for (int rt = 0; rt < 2; ++rt) {
        int r0 = row_base + rt * 16 + q * 4;
        float dv[4];
#pragma unroll
        for (int j = 0; j < 4; ++j) dv[j] = (r0 + j < N) ? dinv[r0 + j] : 0.f;
#pragma unroll
        for (int ct = 0; ct < 4; ++ct) {
            int col = c_base + ct * 16 + lr;
#pragma unroll
            for (int j = 0; j < 4; ++j) {
                int r = r0 + j;
                if (r < N) {
                    float v = fmaf(accl[rt][ct][j], LO_INV, acch[rt][ct][j]);
                    Hh[(size_t)r * 128 + col] = (_Float16)(v * dv[j]);
                }
            }
        }
    }
}

// --- aggregate (CSR gather, fp16 rows): one wave per dst node -----------------
// Half-wave paired-row form: lane loads uint2 (8B); lanes 0-31 cover the full
// 256B row of edge j, lanes 32-63 of edge j+1 -> 512B per instruction pair.
// Combine halves with shfl_xor(32); epilogue/store in lanes < 32.
__global__ __launch_bounds__(256) void k_aggregate_f16(const int* __restrict__ csr_src,
                                                       const int* __restrict__ rowptr,
                                                       const float* __restrict__ dinv,
                                                       const _Float16* __restrict__ Hh,
                                                       const float* __restrict__ bias,
                                                       _Float16* __restrict__ Ah, int N) {
    int d = blockIdx.x * 4 + (threadIdx.x >> 6);
    if (d >= N) return;
    const int lane = threadIdx.x & 63;
    const int h = lane >> 5;        // edge-pair half
    const int il = lane & 31;       // uint2 position within row (32 x 8B = 256B)
    const uint2* Hu = (const uint2*)Hh;   // 32 uint2 per row

    int beg = rowptr[d], end = rowptr[d + 1];
    union PK2 { uint2 u; _Float16 hh[4]; };

    float a0 = 0.f, a1 = 0.f, a2 = 0.f, a3 = 0.f;

    int j = beg;
    for (; j + 15 < end; j += 16) {
        int s[8]; PK2 v[8];
#pragma unroll
        for (int u = 0; u < 8; ++u) s[u] = csr_src[j + 2 * u + h];
#pragma unroll
        for (int u = 0; u < 8; ++u) v[u].u = Hu[(size_t)s[u] * 32 + il];
#pragma unroll
        for (int u = 0; u < 8; ++u) {
            a0 += (float)v[u].hh[0]; a1 += (float)v[u].hh[1];
            a2 += (float)v[u].hh[2]; a3 += (float)v[u].hh[3];
        }
    }
    for (; j + 1 < end; j += 2) {
        PK2 v; v.u = Hu[(size_t)csr_src[j + h] * 32 + il];
        a0 += (float)v.hh[0]; a1 += (float)v.hh[1];
        a2 += (float)v.hh[2]; a3 += (float)v.hh[3];
    }
    if (j < end && h == 0) {    // odd trailing edge: half 0 only
        PK2 v; v.u = Hu[(size_t)csr_src[j] * 32 + il];
        a0 += (float)v.hh[0]; a1 += (float)v.hh[1];
        a2 += (float)v.hh[2]; a3 += (float)v.hh[3];
    }

    // combine edge-halves
    a0 += __shfl_xor(a0, 32);
    a1 += __shfl_xor(a1, 32);
    a2 += __shfl_xor(a2, 32);
    a3 += __shfl_xor(a3, 32);

    if (h == 0) {
        PK2 sv; sv.u = Hu[(size_t)d * 32 + il];   // self term
        a0 += (float)sv.hh[0]; a1 += (float)sv.hh[1];
        a2 += (float)sv.hh[2]; a3 += (float)sv.hh[3];
        float dd = dinv[d];
        float4 b4 = ((const float4*)bias)[il];
        a0 = fmaxf(fmaf(dd, a0, b4.x), 0.f);
        a1 = fmaxf(fmaf(dd, a1, b4.y), 0.f);
        a2 = fmaxf(fmaf(dd, a2, b4.z), 0.f);
        a3 = fmaxf(fmaf(dd, a3, b4.w), 0.f);
        PK2 o;
        o.hh[0] = (_Float16)a0; o.hh[1] = (_Float16)a1;
        o.hh[2] = (_Float16)a2; o.hh[3] = (_Float16)a3;
        ((uint2*)Ah)[(size_t)d * 32 + il] = o.u;
    }
}

// --- pool: pooled[g] += A[i] (activations, bias+relu applied), batch sorted ----
__global__ __launch_bounds__(128) void k_pool(const _Float16* __restrict__ A,
                                              const int* __restrict__ batch,
                                              float* __restrict__ pooled,
                                              float* __restrict__ counts, int N) {
    int k = threadIdx.x;
    int i0 = blockIdx.x * 64;
    if (i0 >= N) return;
    int iend = min(i0 + 64, N);
    float acc = 0.f;
    int cnt = 0;
    int cur = batch[i0];
    for (int i = i0; i < iend; ++i) {
        int g = batch[i];
        if (g != cur) {
            ATOMIC_ADD_F32(&pooled[cur * 128 + k], acc);
            if (k == 0) ATOMIC_ADD_F32(&counts[cur], (float)cnt);
            acc = 0.f; cnt = 0; cur = g;
        }
        acc += (float)A[(size_t)i * 128 + k];
        cnt++;
    }
    ATOMIC_ADD_F32(&pooled[cur * 128 + k], acc);
    if (k == 0) ATOMIC_ADD_F32(&counts[cur], (float)cnt);
}

// --- finalize: global_mean + head ---------------------------------------------
__global__ __launch_bounds__(128) void k_finalize(const float* __restrict__ pooled,
                                                  const float* __restrict__ counts,
                                                  const float* __restrict__ Wl,
                                                  const float* __restrict__ bl,
                                                  float* __restrict__ out) {
    int g = blockIdx.x;
    int t = threadIdx.x;
    __shared__ float m[128];
    float c = fmaxf(counts[g], 1.f);
    float mean = pooled[g * 128 + t] / c;
    out[NG * 10 + g * 128 + t] = mean;
    m[t] = mean;
    __syncthreads();
    if (t < 10) {
        float acc = bl[t];
#pragma unroll 16
        for (int k = 0; k < 128; ++k) acc = fmaf(m[k], Wl[k * 10 + t], acc);
        out[g * 10 + t] = acc;
    }
}

// ---------------------------------------------------------------------------
extern "C" void kernel_launch(void* const* d_in, const int* in_sizes, int n_in,
                              void* d_out, int out_size, void* d_ws, size_t ws_size,
                              hipStream_t stream) {
    const float* x     = (const float*)d_in[0];
    const int*   ei    = (const int*)d_in[1];
    const int*   batch = (const int*)d_in[2];
    const float* Wt[4] = { (const float*)d_in[3], (const float*)d_in[5],
                           (const float*)d_in[7], (const float*)d_in[9] };
    const float* bt[4] = { (const float*)d_in[4], (const float*)d_in[6],
                           (const float*)d_in[8], (const float*)d_in[10] };
    const float* Wl = (const float*)d_in[11];
    const float* bl = (const float*)d_in[12];
    float* out = (float*)d_out;

    const int N = in_sizes[0] / 128;
    const int E = in_sizes[1] / 2;
    const int* src = ei;
    const int* dst = ei + E;

    // workspace layout
    char* p = (char*)d_ws;
    _Float16* Hh    = (_Float16*)p;  p += (size_t)N * 128 * 2;
    _Float16* Ah    = (_Float16*)p;  p += (size_t)N * 128 * 2;
    float* dinv     = (float*)p;     p += (size_t)N * 4;
    int*   deg      = (int*)p;       p += (size_t)N * 4;
    int*   rowptr   = (int*)p;       p += (size_t)(N + 1) * 4;
    int*   cursor   = (int*)p;       p += (size_t)N * 4;
    int*   csr_src  = (int*)p;       p += (size_t)E * 4;
    int*   partials = (int*)p;       p += 512 * 4;
    float* pooled   = (float*)p;     p += (size_t)NG * 128 * 4;
    float* counts   = (float*)p;     p += (size_t)NG * 4;
    _Float16* Wsp   = (_Float16*)p;  p += 4 * 2 * 128 * 128 * 2;

    const int nblk = (N + 255) / 256;

    // degrees (edge count only; self-loop folded into dinv = rsqrt(deg+1))
    hipMemsetAsync(deg, 0, (size_t)N * 4, stream);
    k_deg_count_xcd<<<2048, 256, 0, stream>>>(dst, deg, E, N);

    // CSR build (by dst); scan fused with dinv + cursor seed
    k_scan_local<<<nblk, 256, 0, stream>>>(deg, rowptr, partials, dinv, N);
    k_scan_partials<<<1, 512, 0, stream>>>(partials, nblk);
    k_scan_apply<<<nblk, 256, 0, stream>>>(deg, rowptr, cursor, partials, N);
    k_csr_fill_xcd<<<2048, 256, 0, stream>>>(src, dst, cursor, csr_src, E, N);

    // weight splits (one launch)
    WSplitArgs wa;
    _Float16* Wth[4]; _Float16* Wtl[4];
    for (int l = 0; l < 4; ++l) {
        Wth[l] = Wsp + (size_t)l * 2 * 16384;
        Wtl[l] = Wth[l] + 16384;
        wa.W[l] = Wt[l];
        wa.Wth[l] = Wth[l];
        wa.Wtl[l] = Wtl[l];
    }
    k_wsplit4<<<256, 256, 0, stream>>>(wa);

    // layers (layer 0 GEMM reads fp32 X directly)
    const int gemm_blocks = (N + 63) / 64;
    const int agg_blocks = (N + 3) / 4;
    k_gemm_f16<1><<<gemm_blocks, 256, 0, stream>>>(x, Wth[0], Wtl[0], dinv, Hh, N);
    k_aggregate_f16<<<agg_blocks, 256, 0, stream>>>(csr_src, rowptr, dinv, Hh, bt[0], Ah, N);
    for (int l = 1; l < 4; ++l) {
        k_gemm_f16<0><<<gemm_blocks, 256, 0, stream>>>(Ah, Wth[l], Wtl[l], dinv, Hh, N);
        k_aggregate_f16<<<agg_blocks, 256, 0, stream>>>(csr_src, rowptr, dinv, Hh, bt[l], Ah, N);
    }

    // pool + head
    hipMemsetAsync(pooled, 0, (size_t)(NG * 128 + NG) * 4, stream);
    k_pool<<<(N + 63) / 64, 128, 0, stream>>>(Ah, batch, pooled, counts, N);
    k_finalize<<<NG, 128, 0, stream>>>(pooled, counts, Wl, bl, out);
}

// Round 12
// 570.263 us; speedup vs baseline: 1.1762x; 1.1762x over previous
//
#include <hip/hip_runtime.h>

// ---------------------------------------------------------------------------
// GCN forward, fp16 datapath + XCD-partitioned CSR build.
//   GEMM round-12: fragment-major W layout (contiguous 1KB B-frag loads) +
//   LDS-bounced coalesced H stores. Aggregate/prep = round-10 exact.
//   layer: H' = dinv[r] * (A @ W)        (f16 MFMA, 2 products, split acc)
//          A_next[d] = relu( dinv[d]*(sum_{s in N(d)} H'[s] + H'[d]) + b )
// Output: y[512*10] ++ global_mean[512*128], fp32.
// ---------------------------------------------------------------------------

#define ATOMIC_ADD_F32(p, v) __hip_atomic_fetch_add((p), (v), __ATOMIC_RELAXED, __HIP_MEMORY_SCOPE_AGENT)

constexpr int NG = 512;   // NUM_GRAPHS
constexpr float LO_SCALE = 4096.f;      // 2^12
constexpr float LO_INV   = 1.f / 4096.f;

typedef _Float16 half8 __attribute__((ext_vector_type(8)));
typedef float f32x4 __attribute__((ext_vector_type(4)));

// --- degree (XCD-partitioned histogram; deg = in-edge count) -----------------
__global__ __launch_bounds__(256) void k_deg_count_xcd(const int* __restrict__ dst,
                                                       int* __restrict__ deg,
                                                       int E, int N) {
    const int range = blockIdx.x & 7;
    const int chunk = blockIdx.x >> 3;
    const int nchunks = gridDim.x >> 3;
    const int csz = (E + nchunks - 1) / nchunks;
    const int lo = chunk * csz;
    const int hi = min(lo + csz, E);
    const int nr = N / 8;
    const int rlo = range * nr;
    const int rhi = (range == 7) ? N : rlo + nr;
    for (int i = lo + threadIdx.x; i < hi; i += 256) {
        int d = dst[i];
        if (d >= rlo && d < rhi) atomicAdd(&deg[d], 1);
    }
}

// --- exclusive scan of deg -> rowptr; dinv = rsqrt(deg+1) --------------------
__global__ __launch_bounds__(256) void k_scan_local(const int* __restrict__ deg,
                                                    int* __restrict__ rowptr,
                                                    int* __restrict__ partials,
                                                    float* __restrict__ dinv, int N) {
    __shared__ int s[256];
    int t = threadIdx.x;
    int i = blockIdx.x * 256 + t;
    int dg = (i < N) ? deg[i] : 0;
    if (i < N) dinv[i] = rsqrtf((float)(dg + 1));
    s[t] = dg;
    __syncthreads();
#pragma unroll
    for (int off = 1; off < 256; off <<= 1) {
        int add = (t >= off) ? s[t - off] : 0;
        __syncthreads();
        s[t] += add;
        __syncthreads();
    }
    if (i < N) rowptr[i] = s[t] - dg;
    if (t == 255) partials[blockIdx.x] = s[t];
}

__global__ __launch_bounds__(512) void k_scan_partials(int* __restrict__ partials, int nblk) {
    __shared__ int s[512];
    int t = threadIdx.x;
    int v = (t < nblk) ? partials[t] : 0;
    s[t] = v;
    __syncthreads();
#pragma unroll
    for (int off = 1; off < 512; off <<= 1) {
        int add = (t >= off) ? s[t - off] : 0;
        __syncthreads();
        s[t] += add;
        __syncthreads();
    }
    if (t < nblk) partials[t] = s[t] - v;
}

// also seeds cursor = rowptr
__global__ __launch_bounds__(256) void k_scan_apply(const int* __restrict__ deg,
                                                    int* __restrict__ rowptr,
                                                    int* __restrict__ cursor,
                                                    const int* __restrict__ partials, int N) {
    int i = blockIdx.x * 256 + threadIdx.x;
    if (i < N) {
        int r = rowptr[i] + partials[blockIdx.x];
        rowptr[i] = r;
        cursor[i] = r;
        if (i == N - 1) rowptr[N] = r + deg[i];
    }
}

// --- CSR fill, XCD-partitioned ------------------------------------------------
__global__ __launch_bounds__(256) void k_csr_fill_xcd(const int* __restrict__ src,
                                                      const int* __restrict__ dst,
                                                      int* __restrict__ cursor,
                                                      int* __restrict__ csr_src,
                                                      int E, int N) {
    const int range = blockIdx.x & 7;
    const int chunk = blockIdx.x >> 3;
    const int nchunks = gridDim.x >> 3;
    const int csz = (E + nchunks - 1) / nchunks;
    const int lo = chunk * csz;
    const int hi = min(lo + csz, E);
    const int nr = N / 8;
    const int rlo = range * nr;
    const int rhi = (range == 7) ? N : rlo + nr;
    for (int i = lo + threadIdx.x; i < hi; i += 256) {
        int d = dst[i];
        if (d >= rlo && d < rhi) {
            int pos = atomicAdd(&cursor[d], 1);
            csr_src[pos] = src[i];
        }
    }
}

// --- W prep: fragment-major layout, all 4 layers in one launch -----------------
// Element W[k][c] -> lane l = ((k>>3)&3)*16 + (c&15), tile ctile=c>>4, ks=k>>5,
// byte position pos = ((ctile*4+ks)*64 + l)*8 + (k&7). A wave's B-fragment load
// (64 lanes x 8 halfs) is then one contiguous 1KB block.
struct WSplitArgs {
    const float* W[4];
    _Float16* Wth[4];
    _Float16* Wtl[4];
};
__global__ __launch_bounds__(256) void k_wsplit4(WSplitArgs a) {
    int idx = blockIdx.x * 256 + threadIdx.x;   // 4 * 16384 total
    int layer = idx >> 14;
    int e = idx & 16383;
    int k = e >> 7, c = e & 127;
    float w = a.W[layer][e];
    _Float16 hi = (_Float16)w;
    float lo = (w - (float)hi) * LO_SCALE;
    int ctile = c >> 4, lr = c & 15;
    int ks = k >> 5, q = (k >> 3) & 3, ee = k & 7;
    int pos = (((ctile * 4 + ks) * 64) + q * 16 + lr) * 8 + ee;
    a.Wth[layer][pos] = hi;
    a.Wtl[layer][pos] = (_Float16)lo;
}

// --- GEMM: H' = dinv[r] * (A @ W), f16 MFMA, 2 products, split accumulator ---
// AFP32=1: A is fp32 (layer 0, reads X directly); else fp16.
// W loads are fragment-major (contiguous per wave); H stores bounce through LDS
// for full-line coalescing.
template <int AFP32>
__global__ __launch_bounds__(256) void k_gemm_f16(const void* __restrict__ Aptr,
                                                  const _Float16* __restrict__ Wth,
                                                  const _Float16* __restrict__ Wtl,
                                                  const float* __restrict__ dinv,
                                                  _Float16* __restrict__ Hh, int N) {
    __shared__ _Float16 Hs[64][136];   // 272B row stride: low-conflict scalar stores
    const int tid = threadIdx.x;
    const int wave = tid >> 6;
    const int l = tid & 63;
    const int wrow = wave & 1;
    const int wcol = wave >> 1;
    const int lr = l & 15;
    const int q = l >> 4;

    const int blk_row0 = blockIdx.x * 64;
    const int row_base = blk_row0 + wrow * 32;
    const int c_base = wcol * 64;

    f32x4 acch[2][4], accl[2][4];
#pragma unroll
    for (int rt = 0; rt < 2; ++rt)
#pragma unroll
        for (int ct = 0; ct < 4; ++ct) {
            acch[rt][ct] = (f32x4){0.f, 0.f, 0.f, 0.f};
            accl[rt][ct] = (f32x4){0.f, 0.f, 0.f, 0.f};
        }

#pragma unroll
    for (int ks = 0; ks < 4; ++ks) {
        const int koff = ks * 32 + q * 8;

        half8 bh[4], bl[4];
#pragma unroll
        for (int ct = 0; ct < 4; ++ct) {
            size_t off = (size_t)(((wcol * 4 + ct) * 4 + ks) * 64 + l) * 8;
            bh[ct] = *(const half8*)(Wth + off);
            bl[ct] = *(const half8*)(Wtl + off);
        }

        half8 a[2];
#pragma unroll
        for (int rt = 0; rt < 2; ++rt) {
            int r = row_base + rt * 16 + lr;
            if (r >= N) r = N - 1;                 // clamp; stores guarded
            if constexpr (AFP32) {
                const float* xp = (const float*)Aptr + (size_t)r * 128 + koff;
                float4 f0 = *(const float4*)xp;
                float4 f1 = *(const float4*)(xp + 4);
                half8 h;
                h[0] = (_Float16)f0.x; h[1] = (_Float16)f0.y;
                h[2] = (_Float16)f0.z; h[3] = (_Float16)f0.w;
                h[4] = (_Float16)f1.x; h[5] = (_Float16)f1.y;
                h[6] = (_Float16)f1.z; h[7] = (_Float16)f1.w;
                a[rt] = h;
            } else {
                a[rt] = *(const half8*)((const _Float16*)Aptr + (size_t)r * 128 + koff);
            }
        }

#pragma unroll
        for (int rt = 0; rt < 2; ++rt)
#pragma unroll
            for (int ct = 0; ct < 4; ++ct) {
                acch[rt][ct] = __builtin_amdgcn_mfma_f32_16x16x32_f16(a[rt], bh[ct], acch[rt][ct], 0, 0, 0);
                accl[rt][ct] = __builtin_amdgcn_mfma_f32_16x16x32_f16(a[rt], bl[ct], accl[rt][ct], 0, 0, 0);
            }
    }

    // epilogue: combine, x dinv, scalar-store to LDS tile
#pragma unroll
    for (int rt = 0; rt < 2; ++rt) {
        int lrow0 = wrow * 32 + rt * 16 + q * 4;   // local row base
        int gr0 = blk_row0 + lrow0;
        float dv[4];
#pragma unroll
        for (int j = 0; j < 4; ++j) dv[j] = (gr0 + j < N) ? dinv[gr0 + j] : 0.f;
#pragma unroll
        for (int ct = 0; ct < 4; ++ct) {
            int col = c_base + ct * 16 + lr;
#pragma unroll
            for (int j = 0; j < 4; ++j) {
                float v = fmaf(accl[rt][ct][j], LO_INV, acch[rt][ct][j]);
                Hs[lrow0 + j][col] = (_Float16)(v * dv[j]);
            }
        }
    }
    __syncthreads();

    // block-wide coalesced copy-out: 64 rows x 32 uint2
#pragma unroll
    for (int it = 0; it < 8; ++it) {
        int idx = it * 256 + tid;
        int row = idx >> 5, c2 = idx & 31;
        int gr = blk_row0 + row;
        if (gr < N) {
            uint2 v = *(const uint2*)&Hs[row][c2 * 4];
            ((uint2*)Hh)[(size_t)gr * 32 + c2] = v;
        }
    }
}

// --- aggregate (CSR gather, fp16 rows): one wave per dst node -----------------
// round-10 exact form: 8-deep unroll, plain cached loads (VGPR 20).
__global__ __launch_bounds__(256) void k_aggregate_f16(const int* __restrict__ csr_src,
                                                       const int* __restrict__ rowptr,
                                                       const float* __restrict__ dinv,
                                                       const _Float16* __restrict__ Hh,
                                                       const float* __restrict__ bias,
                                                       _Float16* __restrict__ Ah, int N) {
    int d = blockIdx.x * 4 + (threadIdx.x >> 6);
    if (d >= N) return;
    const int lane = threadIdx.x & 63;
    const unsigned* Hu = (const unsigned*)Hh;        // 64 dwords per row

    int beg = rowptr[d], end = rowptr[d + 1];
    union PK { unsigned u; _Float16 h[2]; };

    PK sv; sv.u = Hu[(size_t)d * 64 + lane];         // self term
    float ax = (float)sv.h[0];
    float ay = (float)sv.h[1];

    int j = beg;
    for (; j + 7 < end; j += 8) {
        int s[8]; PK v[8];
#pragma unroll
        for (int u = 0; u < 8; ++u) s[u] = csr_src[j + u];
#pragma unroll
        for (int u = 0; u < 8; ++u) v[u].u = Hu[(size_t)s[u] * 64 + lane];
#pragma unroll
        for (int u = 0; u < 8; ++u) {
            ax += (float)v[u].h[0];
            ay += (float)v[u].h[1];
        }
    }
    for (; j < end; ++j) {
        PK v; v.u = Hu[(size_t)csr_src[j] * 64 + lane];
        ax += (float)v.h[0];
        ay += (float)v.h[1];
    }

    float dd = dinv[d];
    float2 b2 = ((const float2*)bias)[lane];
    ax = fmaxf(fmaf(dd, ax, b2.x), 0.f);
    ay = fmaxf(fmaf(dd, ay, b2.y), 0.f);

    PK o; o.h[0] = (_Float16)ax; o.h[1] = (_Float16)ay;
    ((unsigned*)Ah)[(size_t)d * 64 + lane] = o.u;
}

// --- pool: pooled[g] += A[i] (activations, bias+relu applied), batch sorted ----
__global__ __launch_bounds__(128) void k_pool(const _Float16* __restrict__ A,
                                              const int* __restrict__ batch,
                                              float* __restrict__ pooled,
                                              float* __restrict__ counts, int N) {
    int k = threadIdx.x;
    int i0 = blockIdx.x * 64;
    if (i0 >= N) return;
    int iend = min(i0 + 64, N);
    float acc = 0.f;
    int cnt = 0;
    int cur = batch[i0];
    for (int i = i0; i < iend; ++i) {
        int g = batch[i];
        if (g != cur) {
            ATOMIC_ADD_F32(&pooled[cur * 128 + k], acc);
            if (k == 0) ATOMIC_ADD_F32(&counts[cur], (float)cnt);
            acc = 0.f; cnt = 0; cur = g;
        }
        acc += (float)A[(size_t)i * 128 + k];
        cnt++;
    }
    ATOMIC_ADD_F32(&pooled[cur * 128 + k], acc);
    if (k == 0) ATOMIC_ADD_F32(&counts[cur], (float)cnt);
}

// --- finalize: global_mean + head ---------------------------------------------
__global__ __launch_bounds__(128) void k_finalize(const float* __restrict__ pooled,
                                                  const float* __restrict__ counts,
                                                  const float* __restrict__ Wl,
                                                  const float* __restrict__ bl,
                                                  float* __restrict__ out) {
    int g = blockIdx.x;
    int t = threadIdx.x;
    __shared__ float m[128];
    float c = fmaxf(counts[g], 1.f);
    float mean = pooled[g * 128 + t] / c;
    out[NG * 10 + g * 128 + t] = mean;
    m[t] = mean;
    __syncthreads();
    if (t < 10) {
        float acc = bl[t];
#pragma unroll 16
        for (int k = 0; k < 128; ++k) acc = fmaf(m[k], Wl[k * 10 + t], acc);
        out[g * 10 + t] = acc;
    }
}

// ---------------------------------------------------------------------------
extern "C" void kernel_launch(void* const* d_in, const int* in_sizes, int n_in,
                              void* d_out, int out_size, void* d_ws, size_t ws_size,
                              hipStream_t stream) {
    const float* x     = (const float*)d_in[0];
    const int*   ei    = (const int*)d_in[1];
    const int*   batch = (const int*)d_in[2];
    const float* Wt[4] = { (const float*)d_in[3], (const float*)d_in[5],
                           (const float*)d_in[7], (const float*)d_in[9] };
    const float* bt[4] = { (const float*)d_in[4], (const float*)d_in[6],
                           (const float*)d_in[8], (const float*)d_in[10] };
    const float* Wl = (const float*)d_in[11];
    const float* bl = (const float*)d_in[12];
    float* out = (float*)d_out;

    const int N = in_sizes[0] / 128;
    const int E = in_sizes[1] / 2;
    const int* src = ei;
    const int* dst = ei + E;

    // workspace layout
    char* p = (char*)d_ws;
    _Float16* Hh    = (_Float16*)p;  p += (size_t)N * 128 * 2;
    _Float16* Ah    = (_Float16*)p;  p += (size_t)N * 128 * 2;
    float* dinv     = (float*)p;     p += (size_t)N * 4;
    int*   deg      = (int*)p;       p += (size_t)N * 4;
    int*   rowptr   = (int*)p;       p += (size_t)(N + 1) * 4;
    int*   cursor   = (int*)p;       p += (size_t)N * 4;
    int*   csr_src  = (int*)p;       p += (size_t)E * 4;
    int*   partials = (int*)p;       p += 512 * 4;
    float* pooled   = (float*)p;     p += (size_t)NG * 128 * 4;
    float* counts   = (float*)p;     p += (size_t)NG * 4;
    _Float16* Wsp   = (_Float16*)p;  p += 4 * 2 * 128 * 128 * 2;

    const int nblk = (N + 255) / 256;

    // degrees (edge count only; self-loop folded into dinv = rsqrt(deg+1))
    hipMemsetAsync(deg, 0, (size_t)N * 4, stream);
    k_deg_count_xcd<<<2048, 256, 0, stream>>>(dst, deg, E, N);

    // CSR build (by dst); scan fused with dinv + cursor seed
    k_scan_local<<<nblk, 256, 0, stream>>>(deg, rowptr, partials, dinv, N);
    k_scan_partials<<<1, 512, 0, stream>>>(partials, nblk);
    k_scan_apply<<<nblk, 256, 0, stream>>>(deg, rowptr, cursor, partials, N);
    k_csr_fill_xcd<<<2048, 256, 0, stream>>>(src, dst, cursor, csr_src, E, N);

    // weight splits (one launch, fragment-major layout)
    WSplitArgs wa;
    _Float16* Wth[4]; _Float16* Wtl[4];
    for (int l = 0; l < 4; ++l) {
        Wth[l] = Wsp + (size_t)l * 2 * 16384;
        Wtl[l] = Wth[l] + 16384;
        wa.W[l] = Wt[l];
        wa.Wth[l] = Wth[l];
        wa.Wtl[l] = Wtl[l];
    }
    k_wsplit4<<<256, 256, 0, stream>>>(wa);

    // layers (layer 0 GEMM reads fp32 X directly)
    const int gemm_blocks = (N + 63) / 64;
    const int agg_blocks = (N + 3) / 4;
    k_gemm_f16<1><<<gemm_blocks, 256, 0, stream>>>(x, Wth[0], Wtl[0], dinv, Hh, N);
    k_aggregate_f16<<<agg_blocks, 256, 0, stream>>>(csr_src, rowptr, dinv, Hh, bt[0], Ah, N);
    for (int l = 1; l < 4; ++l) {
        k_gemm_f16<0><<<gemm_blocks, 256, 0, stream>>>(Ah, Wth[l], Wtl[l], dinv, Hh, N);
        k_aggregate_f16<<<agg_blocks, 256, 0, stream>>>(csr_src, rowptr, dinv, Hh, bt[l], Ah, N);
    }

    // pool + head
    hipMemsetAsync(pooled, 0, (size_t)(NG * 128 + NG) * 4, stream);
    k_pool<<<(N + 63) / 64, 128, 0, stream>>>(Ah, batch, pooled, counts, N);
    k_finalize<<<NG, 128, 0, stream>>>(pooled, counts, Wl, bl, out);
}